// Round 16
// baseline (26.224 us; speedup 1.0000x reference)
//
#include <hip/hip_runtime.h>

#define NE 19
#define CIN 64
#define Z1T_STRIDE 80          // bytes per Z1T row (32 bf16 of 40); 16B-aligned, 2-way banks = free
#define SLICE 5120             // per-graph slice: Z1T (64*80), reused as f32 out-bounce (4864 B)
#define WS_AFRAG 16384         // ws: [0,16K) Wc B-frags; [16K,18K) A-mix A-frags

typedef float f32x4 __attribute__((ext_vector_type(4)));
typedef __bf16 bf16x4 __attribute__((ext_vector_type(4)));
typedef __bf16 bf16x8 __attribute__((ext_vector_type(8)));

__device__ __forceinline__ int swz(int row, int byteoff) {
  return row * 256 + (byteoff ^ ((row & 7) << 4));
}
// Native casts -> compiler emits v_cvt_pk_bf16_f32 (1 instr / 2 values) vs
// 4-op bit-hack (m240: plain cast is the fast path on gfx950).
__device__ __forceinline__ bf16x8 packW(const float* q) {
  f32x4 a = *(const f32x4*)q;
  f32x4 b = *(const f32x4*)(q + 4);
  bf16x8 h;
  h[0]=(__bf16)a[0]; h[1]=(__bf16)a[1]; h[2]=(__bf16)a[2]; h[3]=(__bf16)a[3];
  h[4]=(__bf16)b[0]; h[5]=(__bf16)b[1]; h[6]=(__bf16)b[2]; h[7]=(__bf16)b[3];
  return h;
}

// K1 (5 blocks): pack Wc B-frags + softplus(A) A-frags (bf16) into workspace.
// B-frag fid = ((p*2+kt)*4+nt)*64+lane, p0=Wrel p1=Wroot.
__global__ void prep_kernel(const float* __restrict__ ew,
                            const float* __restrict__ Wrel,
                            const float* __restrict__ Wroot,
                            unsigned char* __restrict__ ws) {
  const int t = threadIdx.x, bid = blockIdx.x;
  if (bid < 4) {
    int fid = bid * 256 + t;
    int p = fid >> 9, kt = (fid >> 8) & 1, nt = (fid >> 6) & 3, lane = fid & 63;
    const float* Wsrc = p ? Wroot : Wrel;
    *(bf16x8*)(ws + fid * 16) =
        packW(Wsrc + (nt * 16 + (lane & 15)) * CIN + kt * 32 + (lane >> 4) * 8);
  } else if (t < 128) {
    // A-mix A-frag: lane holds A[mt*16+(lane&15)][k=(lane>>4)*8+b], A[i][j]=sp(ew[j*19+i])
    int mt = t >> 6, lane = t & 63;
    int row = mt * 16 + (lane & 15);
    bf16x8 h;
    #pragma unroll
    for (int b = 0; b < 8; ++b) {
      int k = (lane >> 4) * 8 + b;
      float v = 0.0f;
      if (row < NE && k < NE) {
        float z = ew[k * NE + row];
        v = fmaxf(z, 0.0f) + log1pf(expf(-fabsf(z)));
      }
      h[b] = (__bf16)v;
    }
    *(bf16x8*)(ws + WS_AFRAG + t * 16) = h;
  }
}

// K2: single-wave blocks, 4 graphs/wave (lookahead-1 x prefetch), zero
// barriers, all compute in MFMA. out = A@(X@Wrel^T) + X@Wroot^T + bias
// launch_bounds (64,2): VGPR cap 128 (cap = 256/min_waves; min-waves>=4
// clamps to 64 and spills — R12).
__global__ __launch_bounds__(64, 2) void gconv_kernel(
    const float* __restrict__ x, const float* __restrict__ bias,
    const unsigned char* __restrict__ ws, float* __restrict__ out)
{
  __shared__ __align__(16) unsigned char sl[2 * SLICE];  // 10240 B

  const int lane = threadIdx.x & 63;
  const int g0 = blockIdx.x * 4;
  const int lr = lane & 15, hg = lane >> 4;
  const bf16x8* frB = (const bf16x8*)ws;

  const bf16x8 afm0 = frB[1024 + lane];
  const bf16x8 afm1 = frB[1088 + lane];
  float biasv[4];
  #pragma unroll
  for (int nt = 0; nt < 4; ++nt) biasv[nt] = bias[nt * 16 + lr];

  // Load one graph's X A-frags (8 x 16B contiguous loads, f32->bf16)
  auto LOADAF = [&](bf16x8 af[2][2], int g) {
    const float* xg = x + (long long)g * NE * CIN;
    #pragma unroll
    for (int mt = 0; mt < 2; ++mt) {
      int rr = mt * 16 + lr; if (rr > NE - 1) rr = NE - 1;  // dup rows, writes guarded
      const float* xr = xg + rr * CIN + hg * 8;
      #pragma unroll
      for (int kt = 0; kt < 2; ++kt) af[mt][kt] = packW(xr + kt * 32);
    }
  };

  // Full per-graph pipeline. BOTH halves' B-frags are loaded up front so
  // half-2's frags arrive during half-1's MFMA (no mid-graph L2 stall).
  auto PROC = [&](bf16x8 af[2][2], unsigned char* z1, int g) {
    bf16x8 bfa[8], bfb[8];
    #pragma unroll
    for (int i = 0; i < 8; ++i) bfa[i] = frB[i * 64 + lane];
    #pragma unroll
    for (int i = 0; i < 8; ++i) bfb[i] = frB[(8 + i) * 64 + lane];

    // half 1: Z1 = X @ Wrel^T
    f32x4 zacc[2][4];
    #pragma unroll
    for (int mt = 0; mt < 2; ++mt)
      #pragma unroll
      for (int nt = 0; nt < 4; ++nt) { zacc[mt][nt][0]=0.f; zacc[mt][nt][1]=0.f; zacc[mt][nt][2]=0.f; zacc[mt][nt][3]=0.f; }
    #pragma unroll
    for (int nt = 0; nt < 4; ++nt)
      #pragma unroll
      for (int mt = 0; mt < 2; ++mt) {
        zacc[mt][nt] = __builtin_amdgcn_mfma_f32_16x16x32_bf16(
            af[mt][0], bfa[nt], zacc[mt][nt], 0, 0, 0);
        zacc[mt][nt] = __builtin_amdgcn_mfma_f32_16x16x32_bf16(
            af[mt][1], bfa[4 + nt], zacc[mt][nt], 0, 0, 0);
      }
    // bounce Z1 -> Z1T[c][j] bf16 (j 19..31 zeroed), 8 ds_write_b64
    #pragma unroll
    for (int nt = 0; nt < 4; ++nt) {
      int c = nt * 16 + lr;
      bf16x4 h0;
      #pragma unroll
      for (int b = 0; b < 4; ++b) h0[b] = (__bf16)zacc[0][nt][b];
      *(bf16x4*)(z1 + c * Z1T_STRIDE + hg * 8) = h0;
      bf16x4 h1;
      #pragma unroll
      for (int b = 0; b < 4; ++b) {
        int j = 16 + hg * 4 + b;
        h1[b] = (j < NE) ? (__bf16)zacc[1][nt][b] : (__bf16)0.0f;
      }
      *(bf16x4*)(z1 + c * Z1T_STRIDE + 32 + hg * 8) = h1;
    }

    // half 2: acc = X @ Wroot^T
    f32x4 acc[2][4];
    #pragma unroll
    for (int mt = 0; mt < 2; ++mt)
      #pragma unroll
      for (int nt = 0; nt < 4; ++nt) { acc[mt][nt][0]=0.f; acc[mt][nt][1]=0.f; acc[mt][nt][2]=0.f; acc[mt][nt][3]=0.f; }
    #pragma unroll
    for (int nt = 0; nt < 4; ++nt)
      #pragma unroll
      for (int mt = 0; mt < 2; ++mt) {
        acc[mt][nt] = __builtin_amdgcn_mfma_f32_16x16x32_bf16(
            af[mt][0], bfb[nt], acc[mt][nt], 0, 0, 0);
        acc[mt][nt] = __builtin_amdgcn_mfma_f32_16x16x32_bf16(
            af[mt][1], bfb[4 + nt], acc[mt][nt], 0, 0, 0);
      }
    // mix as MFMA: acc += A @ Z1
    #pragma unroll
    for (int nt = 0; nt < 4; ++nt) {
      bf16x8 zf = *(const bf16x8*)(z1 + (nt * 16 + lr) * Z1T_STRIDE + hg * 16);
      acc[0][nt] = __builtin_amdgcn_mfma_f32_16x16x32_bf16(afm0, zf, acc[0][nt], 0, 0, 0);
      acc[1][nt] = __builtin_amdgcn_mfma_f32_16x16x32_bf16(afm1, zf, acc[1][nt], 0, 0, 0);
    }
    // bias + f32 out-bounce overlaid on the slice (zf reads precede these
    // writes in same-wave program order -> race-free)
    #pragma unroll
    for (int mt = 0; mt < 2; ++mt)
      #pragma unroll
      for (int nt = 0; nt < 4; ++nt)
        #pragma unroll
        for (int b = 0; b < 4; ++b) {
          int row = mt * 16 + hg * 4 + b;
          if (row < NE)
            *(float*)(&z1[swz(row, (nt * 16 + lr) * 4)]) = acc[mt][nt][b] + biasv[nt];
        }
    // coalesced epilogue: 1KB contiguous per wave instruction
    const long long orow0 = (long long)g * NE;
    #pragma unroll
    for (int p = 0; p < 5; ++p) {
      int q = p * 64 + lane;
      if (q < NE * 16) {
        int r = q >> 4, c = q & 15;
        f32x4 v = *(const f32x4*)(&z1[swz(r, c * 16)]);
        *(f32x4*)(out + (orow0 + r) * CIN + c * 4) = v;
      }
    }
  };

  // 4 graphs, lookahead-1 x prefetch; slices alternate (same-wave program
  // order makes slice reuse race-free).
  bf16x8 afa[2][2], afb[2][2];
  LOADAF(afa, g0);
  LOADAF(afb, g0 + 1);
  PROC(afa, sl,         g0);
  LOADAF(afa, g0 + 2);
  PROC(afb, sl + SLICE, g0 + 1);
  LOADAF(afb, g0 + 3);
  PROC(afa, sl,         g0 + 2);
  PROC(afb, sl + SLICE, g0 + 3);
}

extern "C" void kernel_launch(void* const* d_in, const int* in_sizes, int n_in,
                              void* d_out, int out_size, void* d_ws, size_t ws_size,
                              hipStream_t stream) {
  const float* x    = (const float*)d_in[0];
  const float* ew   = (const float*)d_in[1];
  const float* Wrel = (const float*)d_in[2];
  const float* Wroot= (const float*)d_in[3];
  const float* bias = (const float*)d_in[4];
  float* out = (float*)d_out;
  unsigned char* ws = (unsigned char*)d_ws;   // needs 18432 B

  prep_kernel<<<5, 256, 0, stream>>>(ew, Wrel, Wroot, ws);

  const int ngraphs = (in_sizes[0] / CIN) / NE;   // 8192
  const int nblocks = ngraphs / 4;                // 2048 single-wave blocks
  gconv_kernel<<<nblocks, 64, 0, stream>>>(x, bias, ws, out);
}